// Round 3
// baseline (31.145 us; speedup 1.0000x reference)
//
#include <hip/hip_runtime.h>
#include <hip/hip_bf16.h>

#define BATCH 4096
#define FEAT  64
#define LW    64
#define KH    5
#define KW    9
#define RH    5
#define PADL  4
#define CUT   5    // mask: h==KH-1 && ww>=CUT -> zero weight
#define NW    8    // waves per conv block

typedef __attribute__((ext_vector_type(8))) short bf16x8;
typedef __attribute__((ext_vector_type(4))) float f32x4;
typedef const __attribute__((address_space(1))) void* gas_ptr;
typedef __attribute__((address_space(3))) void* las_ptr;

__device__ __forceinline__ short f2bf(float x) {
    union { float f; unsigned u; } v; v.f = x;
    unsigned r = v.u + 0x7FFFu + ((v.u >> 16) & 1u);  // RNE
    return (short)(r >> 16);
}

__device__ __forceinline__ bf16x8 cvt8(f32x4 x0, f32x4 x1) {
    bf16x8 a;
    a[0]=f2bf(x0[0]); a[1]=f2bf(x0[1]); a[2]=f2bf(x0[2]); a[3]=f2bf(x0[3]);
    a[4]=f2bf(x1[0]); a[5]=f2bf(x1[1]); a[6]=f2bf(x1[2]); a[7]=f2bf(x1[3]);
    return a;
}

// Weights: mask + runtime zeroing (pad cols / shift row) + transpose + bf16.
// W[h][ww][c][f] f32 -> Wt[p][f][c] bf16. (Unchanged from R2 — verified.)
__global__ __launch_bounds__(256) void wprep_kernel(
    const float* __restrict__ W, const int* __restrict__ idxp,
    short* __restrict__ Wt)
{
    __shared__ short T[64][72];
    const int p = blockIdx.x;            // 0..44
    const int h = p / KW, ww = p % KW;
    const int index = idxp[0];
    int index_w = ((index % LW) + LW) % LW;
    const bool upd   = index >= 0;
    const bool shift = upd && (index_w == 0);
    const bool is_input = upd && (h == KH - 1) && (ww == PADL);
    const int col = index_w - PADL + ww;
    const bool zero = (h == KH - 1 && ww >= CUT)
                   || (!is_input && (col < 0 || col >= LW))
                   || (!is_input && shift && h == KH - 1);
    const int t = threadIdx.x;
    const float* src = W + p * 4096;
    for (int i = 0; i < 16; ++i) {
        int e = i * 256 + t;             // (c,f), f fastest -> coalesced read
        int c = e >> 6, f = e & 63;
        T[f][c] = zero ? (short)0 : f2bf(src[e]);
    }
    __syncthreads();
    short* dst = Wt + p * 4096;
    for (int i = 0; i < 16; ++i) {
        int e = i * 256 + t;             // (f,c), c fastest -> coalesced write
        dst[e] = T[e >> 6][e & 63];
    }
}

// Stage one 16-row x 256B column tile into LDS via global_load_lds.
// Lane l -> (row = l&15, chunk cc = l>>4); instr i covers 16B-chunks c = i*4+cc.
// Resulting LDS layout: tile_byte(c, row) = c*256 + row*16 (2-way banks: free).
__device__ __forceinline__ void stage_slot(
    float (*Abuf)[9][1024], const float* __restrict__ cache,
    const float* __restrict__ inputs, int r0, int hl, int s,
    int index_w, bool upd, bool shift, int lane)
{
    const int row = lane & 15;
    const int cc  = lane >> 4;
    const bool is_in = upd && (hl == KH - 1) && (s == PADL);
    int col = index_w - PADL + s;
    col = min(max(col, 0), LW - 1);                 // clamped; OOB => zero weight
    const int hh = shift ? min(hl + 1, RH - 1) : hl;
    const float* base = is_in
        ? inputs + (long)(r0 + row) * FEAT
        : cache + (long)(r0 + row) * (RH * LW * FEAT) + (hh * LW + col) * FEAT;
    float* dst = &Abuf[hl & 1][s][0];
    #pragma unroll
    for (int i = 0; i < 4; ++i) {
        const float* src = base + (i * 4 + cc) * 4;
        __builtin_amdgcn_global_load_lds((gas_ptr)src, (las_ptr)(dst + i * 256),
                                         16, 0, 0);
    }
}

__device__ __forceinline__ void compute_slot(
    float (*Abuf)[9][1024], const short* __restrict__ Wt,
    int hl, int s, int n, int g, f32x4 acc[4])
{
    const float* tb = &Abuf[hl & 1][s][0];
    const int c0 = 2 * g;
    f32x4 x0 = *(const f32x4*)(tb + (c0    ) * 64 + n * 4);
    f32x4 x1 = *(const f32x4*)(tb + (c0 + 1) * 64 + n * 4);
    f32x4 x2 = *(const f32x4*)(tb + (c0 + 8) * 64 + n * 4);
    f32x4 x3 = *(const f32x4*)(tb + (c0 + 9) * 64 + n * 4);
    bf16x8 a0 = cvt8(x0, x1);
    bf16x8 a1 = cvt8(x2, x3);
    const int p = hl * KW + s;
    const short* wbase = Wt + p * 4096 + n * 64;
    #pragma unroll
    for (int ft = 0; ft < 4; ++ft) {
        bf16x8 b0 = *(const bf16x8*)(wbase + ft * 1024 + g * 8);
        bf16x8 b1 = *(const bf16x8*)(wbase + ft * 1024 + 32 + g * 8);
        acc[ft] = __builtin_amdgcn_mfma_f32_16x16x32_bf16(a0, b0, acc[ft], 0, 0, 0);
        acc[ft] = __builtin_amdgcn_mfma_f32_16x16x32_bf16(a1, b1, acc[ft], 0, 0, 0);
    }
}

template<int W>
__device__ __forceinline__ void wave_loop(
    float (*Abuf)[9][1024], const float* __restrict__ cache,
    const float* __restrict__ inputs, const short* __restrict__ Wt,
    int r0, int index_w, bool upd, bool shift, int lane, int n, int g,
    f32x4 acc[4])
{
    // prologue: stage h=0 and h=1
    stage_slot(Abuf, cache, inputs, r0, 0, W, index_w, upd, shift, lane);
    if constexpr (W == 0)
        stage_slot(Abuf, cache, inputs, r0, 0, 8, index_w, upd, shift, lane);
    stage_slot(Abuf, cache, inputs, r0, 1, W, index_w, upd, shift, lane);
    if constexpr (W == 0)
        stage_slot(Abuf, cache, inputs, r0, 1, 8, index_w, upd, shift, lane);

    #pragma unroll
    for (int hl = 0; hl < KH; ++hl) {
        // counted wait: tolerate next-level stages in flight (in-order retire
        // guarantees stage(hl) complete once only the newest 4/8 remain)
        if constexpr (W == 0) asm volatile("s_waitcnt vmcnt(8)" ::: "memory");
        else                  asm volatile("s_waitcnt vmcnt(4)" ::: "memory");

        compute_slot(Abuf, Wt, hl, W, n, g, acc);
        if constexpr (W == 0) compute_slot(Abuf, Wt, hl, 8, n, g, acc);

        if (hl < KH - 2) {
            // ds_reads of buf[hl&1] must retire before overwriting it
            asm volatile("s_waitcnt lgkmcnt(0)" ::: "memory");
            stage_slot(Abuf, cache, inputs, r0, hl + 2, W, index_w, upd, shift, lane);
            if constexpr (W == 0)
                stage_slot(Abuf, cache, inputs, r0, hl + 2, 8, index_w, upd, shift, lane);
        }
    }
}

__global__ __launch_bounds__(512, 2) void conv_kernel(
    const float* __restrict__ inputs, const float* __restrict__ cache,
    const short* __restrict__ Wt, const float* __restrict__ bias,
    const int* __restrict__ idxp, float* __restrict__ out)
{
    __shared__ float Abuf[2][9][1024];   // 72 KB staging (2 h-levels x 9 slots)
    __shared__ float Lacc[NW][16][65];   // 33 KB K-split partials

    const int t    = threadIdx.x;
    const int lane = t & 63;
    const int wv   = t >> 6;             // 0..7: owns column slot wv (+8 for wv==0)
    const int n    = lane & 15;
    const int g    = lane >> 4;
    const int r0   = blockIdx.x * 16;

    const int index = idxp[0];
    int index_w = ((index % LW) + LW) % LW;
    const bool upd   = index >= 0;
    const bool shift = upd && (index_w == 0);

    f32x4 acc[4] = {{0,0,0,0},{0,0,0,0},{0,0,0,0},{0,0,0,0}};

    switch (wv) {
        case 0: wave_loop<0>(Abuf, cache, inputs, Wt, r0, index_w, upd, shift, lane, n, g, acc); break;
        case 1: wave_loop<1>(Abuf, cache, inputs, Wt, r0, index_w, upd, shift, lane, n, g, acc); break;
        case 2: wave_loop<2>(Abuf, cache, inputs, Wt, r0, index_w, upd, shift, lane, n, g, acc); break;
        case 3: wave_loop<3>(Abuf, cache, inputs, Wt, r0, index_w, upd, shift, lane, n, g, acc); break;
        case 4: wave_loop<4>(Abuf, cache, inputs, Wt, r0, index_w, upd, shift, lane, n, g, acc); break;
        case 5: wave_loop<5>(Abuf, cache, inputs, Wt, r0, index_w, upd, shift, lane, n, g, acc); break;
        case 6: wave_loop<6>(Abuf, cache, inputs, Wt, r0, index_w, upd, shift, lane, n, g, acc); break;
        default: wave_loop<7>(Abuf, cache, inputs, Wt, r0, index_w, upd, shift, lane, n, g, acc); break;
    }

    // D layout: col f = ft*16+n, row m = g*4+i
    #pragma unroll
    for (int ft = 0; ft < 4; ++ft)
        #pragma unroll
        for (int i = 0; i < 4; ++i)
            Lacc[wv][g * 4 + i][ft * 16 + n] = acc[ft][i];

    __syncthreads();

    // Reduce over the 8 waves: thread t -> f = lane, rows m = wv and wv+8
    const int f = lane;
    #pragma unroll
    for (int half = 0; half < 2; ++half) {
        const int m = wv + half * 8;
        float s = bias[f];
        #pragma unroll
        for (int w2 = 0; w2 < NW; ++w2) s += Lacc[w2][m][f];
        out[(long)(r0 + m) * FEAT + f] = s;
    }
}

extern "C" void kernel_launch(void* const* d_in, const int* in_sizes, int n_in,
                              void* d_out, int out_size, void* d_ws, size_t ws_size,
                              hipStream_t stream) {
    const float* inputs = (const float*)d_in[0];
    const float* cache  = (const float*)d_in[1];
    const float* kern   = (const float*)d_in[2];
    const float* bias   = (const float*)d_in[3];
    const int*   idx    = (const int*)d_in[4];
    float* out = (float*)d_out;

    short* Wt = (short*)d_ws;   // 45*4096*2 = 368,640 B
    wprep_kernel<<<KH * KW, 256, 0, stream>>>(kern, idx, Wt);
    conv_kernel<<<BATCH / 16, 512, 0, stream>>>(inputs, cache, Wt, bias, idx, out);
}